// Round 1
// baseline (2662.251 us; speedup 1.0000x reference)
//
#include <hip/hip_runtime.h>
#include <stdint.h>

#define N_TOK   16384
#define DMODEL  1024
#define NEXP    8
#define DFF     4096
#define CAP     8192
#define W_LOAD_C 0.01f

typedef __attribute__((ext_vector_type(8))) short short8;
typedef __attribute__((ext_vector_type(4))) float f32x4;

__device__ __forceinline__ uint16_t f2bf(float f) {
    uint32_t u = __float_as_uint(f);
    uint32_t r = u + 0x7fffu + ((u >> 16) & 1u);
    return (uint16_t)(r >> 16);
}

__device__ __forceinline__ float gelu_tanh(float v) {
    float u = 0.7978845608028654f * (v + 0.044715f * v * v * v);
    float ex = __expf(2.0f * u);
    float th = 1.0f - 2.0f / (ex + 1.0f);
    return 0.5f * v * (1.0f + th);
}

__device__ __forceinline__ void glds16(const uint16_t* g, uint16_t* l) {
    __builtin_amdgcn_global_load_lds(
        (const __attribute__((address_space(1))) void*)g,
        (__attribute__((address_space(3))) void*)l, 16, 0, 0);
}

// ---------------- gating + routing + load-loss accumulation ----------------
__global__ __launch_bounds__(256) void gating_kernel(
    const float* __restrict__ x, const float* __restrict__ noise,
    const float* __restrict__ gate_w, const float* __restrict__ noise_w,
    int* __restrict__ cnt, float* __restrict__ loadAcc,
    int* __restrict__ rowlist, float* __restrict__ slotw)
{
    __shared__ float lred[4][8];
    const int lane = threadIdx.x & 63;
    const int wid  = threadIdx.x >> 6;
    const int gwave = blockIdx.x * 4 + wid;
    float accP = 0.0f;

    for (int t = gwave; t < N_TOK; t += 1024) {
        const float* xr = x + (size_t)t * DMODEL;
        float ag[8] = {0,0,0,0,0,0,0,0};
        float an[8] = {0,0,0,0,0,0,0,0};
        for (int j = 0; j < 16; ++j) {
            int idx = j * 64 + lane;
            float xv = xr[idx];
            const float4* gp  = (const float4*)(gate_w  + idx * 8);
            const float4* np_ = (const float4*)(noise_w + idx * 8);
            float4 g0 = gp[0], g1 = gp[1];
            float4 n0 = np_[0], n1 = np_[1];
            ag[0] += xv * g0.x; ag[1] += xv * g0.y; ag[2] += xv * g0.z; ag[3] += xv * g0.w;
            ag[4] += xv * g1.x; ag[5] += xv * g1.y; ag[6] += xv * g1.z; ag[7] += xv * g1.w;
            an[0] += xv * n0.x; an[1] += xv * n0.y; an[2] += xv * n0.z; an[3] += xv * n0.w;
            an[4] += xv * n1.x; an[5] += xv * n1.y; an[6] += xv * n1.z; an[7] += xv * n1.w;
        }
        #pragma unroll
        for (int m = 32; m >= 1; m >>= 1) {
            #pragma unroll
            for (int e = 0; e < 8; ++e) {
                ag[e] += __shfl_xor(ag[e], m, 64);
                an[e] += __shfl_xor(an[e], m, 64);
            }
        }
        float logit[8], sdv[8];
        #pragma unroll
        for (int e = 0; e < 8; ++e) {
            float a = an[e];
            float sp = (a > 20.0f) ? a : log1pf(expf(a));
            sdv[e] = sp;
            logit[e] = ag[e] + noise[(size_t)t * 8 + e] * sp;
        }
        // top-3 values, top-2 indices (strict > keeps earliest index on ties, as lax.top_k)
        float v1 = -1e30f, v2 = -1e30f, v3 = -1e30f; int i1 = 0, i2 = 0;
        #pragma unroll
        for (int e = 0; e < 8; ++e) {
            float v = logit[e];
            if (v > v1)      { v3 = v2; v2 = v1; i2 = i1; v1 = v; i1 = e; }
            else if (v > v2) { v3 = v2; v2 = v; i2 = e; }
            else if (v > v3) { v3 = v; }
        }
        if (lane < 8) {
            float kth = (lane == i1 || lane == i2) ? v3 : v2;
            float z = (logit[lane] - kth) / sdv[lane];
            accP += 0.5f * erfcf(-z * 0.70710678118654752440f);
        }
        if (lane == 0) {
            float e2 = expf(v2 - v1);
            float inv = 1.0f / (1.0f + e2);
            float w0 = inv, w1v = e2 * inv;
            int p0 = atomicAdd(&cnt[i1], 1);
            int p1 = atomicAdd(&cnt[i2], 1);
            if (p0 < CAP) { rowlist[i1 * CAP + p0] = t; slotw[i1 * CAP + p0] = w0;  }
            if (p1 < CAP) { rowlist[i2 * CAP + p1] = t; slotw[i2 * CAP + p1] = w1v; }
        }
    }
    if (lane < 8) lred[wid][lane] = accP;
    __syncthreads();
    if (threadIdx.x < 8)
        atomicAdd(&loadAcc[threadIdx.x],
                  lred[0][threadIdx.x] + lred[1][threadIdx.x] +
                  lred[2][threadIdx.x] + lred[3][threadIdx.x]);
}

// ---------------- f32 -> bf16 convert (x) ----------------
__global__ __launch_bounds__(256) void convert_x_kernel(
    const float* __restrict__ x, uint16_t* __restrict__ xb)
{
    int i = blockIdx.x * 256 + threadIdx.x;
    float4 v = ((const float4*)x)[i];
    ushort4 o;
    o.x = f2bf(v.x); o.y = f2bf(v.y); o.z = f2bf(v.z); o.w = f2bf(v.w);
    ((ushort4*)xb)[i] = o;
}

// ---------------- per-expert transpose f32 [R][C] -> bf16 [C][R] ----------------
__global__ __launch_bounds__(256) void transpose_w_kernel(
    const float* __restrict__ src, uint16_t* __restrict__ dst, int R, int Cc)
{
    __shared__ float tile[32][33];
    const float* s = src + (size_t)blockIdx.z * R * Cc;
    uint16_t*    d = dst + (size_t)blockIdx.z * R * Cc;
    int c0 = blockIdx.x * 32, r0 = blockIdx.y * 32;
    int tx = threadIdx.x & 31, ty = threadIdx.x >> 5;
    #pragma unroll
    for (int rr = ty; rr < 32; rr += 8)
        tile[rr][tx] = s[(size_t)(r0 + rr) * Cc + c0 + tx];
    __syncthreads();
    #pragma unroll
    for (int rr = ty; rr < 32; rr += 8)
        d[(size_t)(c0 + rr) * R + r0 + tx] = f2bf(tile[tx][rr]);
}

// ---------------- GEMM: 128x128 tile, BK=32, 4 waves, m97 structure ----------------
// A rows: gathered tokens (GATHER) or h slots. B: pre-transposed weights [ncols][KTOT].
// GELU: gelu epilogue, bf16 store to OutBf. ATOMIC: fused combine into OutF.
template<int KTOT, int GATHER, int GELU, int ATOMIC>
__global__ __launch_bounds__(256) void gemm_kernel(
    const uint16_t* __restrict__ Abase,
    const uint16_t* __restrict__ Bfull,
    const int*      __restrict__ rowlist,
    const float*    __restrict__ slotw,
    const int*      __restrict__ cnt,
    const float*    __restrict__ biasFull,
    uint16_t*       __restrict__ OutBf,
    float*          __restrict__ OutF,
    int ncols, int e_base)
{
    __shared__ uint16_t lA[4096];   // 128x32 bf16, fragment-contiguous
    __shared__ uint16_t lB[4096];
    __shared__ int   lT[128];
    __shared__ float lW[128];

    const int zz = blockIdx.z;
    const int e = e_base + zz;
    int ce = cnt[e]; if (ce > CAP) ce = CAP;
    const int row0 = blockIdx.x * 128;
    if (row0 >= ce) return;
    const int n0 = blockIdx.y * 128;

    const int t = threadIdx.x;
    const int lane = t & 63;
    const int wid = t >> 6;
    const int fr = lane & 15;   // fragment row/col (lane&15)
    const int ks = lane >> 4;   // k-slot (lane>>4)

    if (GATHER || ATOMIC) {
        if (t < 128) {
            int r = row0 + t;
            int rc = (r < ce) ? r : (ce - 1);
            lT[t] = rowlist[e * CAP + rc];
            if (ATOMIC) lW[t] = (r < ce) ? slotw[e * CAP + r] : 0.0f;
        }
        __syncthreads();
    }

    const int ra0 = wid * 16 + fr;       // tile-local A/B row for staging instr 0
    const int ra1 = 64 + wid * 16 + fr;  // instr 1
    size_t arow0, arow1;
    if (GATHER) { arow0 = (size_t)lT[ra0]; arow1 = (size_t)lT[ra1]; }
    else        { arow0 = (size_t)zz * CAP + row0 + ra0;
                  arow1 = (size_t)zz * CAP + row0 + ra1; }
    const uint16_t* pA0 = Abase + arow0 * KTOT + ks * 8;
    const uint16_t* pA1 = Abase + arow1 * KTOT + ks * 8;
    const uint16_t* Bp  = Bfull + (size_t)e * ncols * KTOT;
    const uint16_t* pB0 = Bp + (size_t)(n0 + ra0) * KTOT + ks * 8;
    const uint16_t* pB1 = Bp + (size_t)(n0 + ra1) * KTOT + ks * 8;
    uint16_t* dA0 = &lA[t * 8];
    uint16_t* dA1 = &lA[2048 + t * 8];
    uint16_t* dB0 = &lB[t * 8];
    uint16_t* dB1 = &lB[2048 + t * 8];

    f32x4 acc[4][4];
    #pragma unroll
    for (int a = 0; a < 4; ++a)
        #pragma unroll
        for (int b = 0; b < 4; ++b) acc[a][b] = (f32x4){0.f, 0.f, 0.f, 0.f};

    const int wr = wid >> 1, wc = wid & 1;

    for (int k0 = 0; k0 < KTOT; k0 += 32) {
        glds16(pA0 + k0, dA0);
        glds16(pA1 + k0, dA1);
        glds16(pB0 + k0, dB0);
        glds16(pB1 + k0, dB1);
        __syncthreads();
        short8 af[4], bfr[4];
        #pragma unroll
        for (int mi = 0; mi < 4; ++mi)
            af[mi] = *(const short8*)&lA[(wr * 4 + mi) * 512 + lane * 8];
        #pragma unroll
        for (int ni = 0; ni < 4; ++ni)
            bfr[ni] = *(const short8*)&lB[(wc * 4 + ni) * 512 + lane * 8];
        #pragma unroll
        for (int mi = 0; mi < 4; ++mi)
            #pragma unroll
            for (int ni = 0; ni < 4; ++ni)
                acc[mi][ni] = __builtin_amdgcn_mfma_f32_16x16x32_bf16(
                    af[mi], bfr[ni], acc[mi][ni], 0, 0, 0);
        __syncthreads();
    }

    // epilogue: D mapping col = lane&15, row = (lane>>4)*4 + j  [measured m89/m91]
    const int colBase = n0 + wc * 64;
    const float* bias = biasFull + (size_t)e * ncols;
    #pragma unroll
    for (int mi = 0; mi < 4; ++mi) {
        int rloc = wr * 64 + mi * 16 + ks * 4;   // tile-local row
        #pragma unroll
        for (int ni = 0; ni < 4; ++ni) {
            int c = colBase + ni * 16 + fr;
            float bv = bias[c];
            #pragma unroll
            for (int j = 0; j < 4; ++j) {
                float v = acc[mi][ni][j] + bv;
                if (GELU) v = gelu_tanh(v);
                int rl = rloc + j;
                if (ATOMIC) {
                    if (row0 + rl < ce)
                        atomicAdd(&OutF[(size_t)lT[rl] * DMODEL + c], lW[rl] * v);
                } else {
                    OutBf[((size_t)zz * CAP + row0 + rl) * ncols + c] = f2bf(v);
                }
            }
        }
    }
}

// ---------------- load-loss finalize ----------------
__global__ void finalize_kernel(const float* __restrict__ loadAcc, float* __restrict__ out) {
    if (threadIdx.x == 0) {
        float m = 0.f;
        #pragma unroll
        for (int e = 0; e < 8; ++e) m += loadAcc[e];
        m *= 0.125f;
        float v = 0.f;
        #pragma unroll
        for (int e = 0; e < 8; ++e) { float d0 = loadAcc[e] - m; v += d0 * d0; }
        v *= (1.0f / 7.0f);   // ddof=1
        out[(size_t)N_TOK * DMODEL] = W_LOAD_C * v / (m * m);
    }
}

extern "C" void kernel_launch(void* const* d_in, const int* in_sizes, int n_in,
                              void* d_out, int out_size, void* d_ws, size_t ws_size,
                              hipStream_t stream) {
    const float* x       = (const float*)d_in[0];
    const float* noise   = (const float*)d_in[1];
    const float* gate_w  = (const float*)d_in[2];
    const float* noise_w = (const float*)d_in[3];
    const float* w1      = (const float*)d_in[4];
    const float* b1      = (const float*)d_in[5];
    const float* w2      = (const float*)d_in[6];
    const float* b2      = (const float*)d_in[7];
    float* out = (float*)d_out;
    char* ws = (char*)d_ws;

    int*      cnt     = (int*)(ws + 0);
    float*    loadAcc = (float*)(ws + 256);
    int*      rowlist = (int*)(ws + 4096);
    float*    slotw   = (float*)(ws + 266240);
    uint16_t* xb      = (uint16_t*)(ws + 528384);
    uint16_t* w1t     = (uint16_t*)(ws + 34082816);
    uint16_t* w2t     = (uint16_t*)(ws + 101191680);
    uint16_t* h       = (uint16_t*)(ws + 168300544);

    const bool full = ws_size >= 705171456ull;  // h for all 8 experts at capacity

    hipMemsetAsync(ws, 0, 512, stream);
    hipMemsetAsync(d_out, 0, (size_t)out_size * sizeof(float), stream);

    gating_kernel<<<256, 256, 0, stream>>>(x, noise, gate_w, noise_w,
                                           cnt, loadAcc, rowlist, slotw);
    convert_x_kernel<<<16384, 256, 0, stream>>>(x, xb);
    transpose_w_kernel<<<dim3(128, 32, 8), 256, 0, stream>>>(w1, w1t, 1024, 4096);
    transpose_w_kernel<<<dim3(32, 128, 8), 256, 0, stream>>>(w2, w2t, 4096, 1024);
    finalize_kernel<<<1, 64, 0, stream>>>(loadAcc, out);

    if (full) {
        gemm_kernel<1024, 1, 1, 0><<<dim3(64, 32, 8), 256, 0, stream>>>(
            xb, w1t, rowlist, slotw, cnt, b1, h, nullptr, DFF, 0);
        gemm_kernel<4096, 0, 0, 1><<<dim3(64, 8, 8), 256, 0, stream>>>(
            h, w2t, rowlist, slotw, cnt, b2, nullptr, out, DMODEL, 0);
    } else {
        for (int e = 0; e < NEXP; ++e) {
            gemm_kernel<1024, 1, 1, 0><<<dim3(64, 32, 1), 256, 0, stream>>>(
                xb, w1t, rowlist, slotw, cnt, b1, h, nullptr, DFF, e);
            gemm_kernel<4096, 0, 0, 1><<<dim3(64, 8, 1), 256, 0, stream>>>(
                h, w2t, rowlist, slotw, cnt, b2, nullptr, out, DMODEL, e);
        }
    }
}

// Round 2
// 1466.883 us; speedup vs baseline: 1.8149x; 1.8149x over previous
//
#include <hip/hip_runtime.h>
#include <stdint.h>

#define N_TOK   16384
#define DMODEL  1024
#define NEXP    8
#define DFF     4096
#define CAP     8192
#define MAXBLK  264          // 32768/128 + 8 (per-expert 128-row padding)
#define W_LOAD_C 0.01f

typedef __attribute__((ext_vector_type(8))) short short8;
typedef __attribute__((ext_vector_type(4))) float f32x4;

__device__ __forceinline__ uint16_t f2bf(float f) {
    uint32_t u = __float_as_uint(f);
    uint32_t r = u + 0x7fffu + ((u >> 16) & 1u);
    return (uint16_t)(r >> 16);
}

__device__ __forceinline__ float gelu_tanh(float v) {
    float u = 0.7978845608028654f * (v + 0.044715f * v * v * v);
    float ex = __expf(2.0f * u);
    float th = 1.0f - 2.0f / (ex + 1.0f);
    return 0.5f * v * (1.0f + th);
}

__device__ __forceinline__ void glds16(const uint16_t* g, uint16_t* l) {
    __builtin_amdgcn_global_load_lds(
        (const __attribute__((address_space(1))) void*)g,
        (__attribute__((address_space(3))) void*)l, 16, 0, 0);
}

// ---------------- gating + routing + load-loss + fused x->bf16 ----------------
// 2048 blocks x 512 threads; one token per wave. Dot-product code kept
// bitwise-identical to the round-1 passing version (same FMA/shuffle order).
__global__ __launch_bounds__(512) void gating_kernel(
    const float* __restrict__ x, const float* __restrict__ noise,
    const float* __restrict__ gate_w, const float* __restrict__ noise_w,
    int* __restrict__ cnt, float* __restrict__ loadAcc,
    int* __restrict__ rowlist, float* __restrict__ slotw,
    uint16_t* __restrict__ xb)
{
    __shared__ float lp[8][8];
    __shared__ int   se1[8], se2[8];
    __shared__ float sw1[8], sw2[8];

    const int lane = threadIdx.x & 63;
    const int wid  = threadIdx.x >> 6;
    const int t = blockIdx.x * 8 + wid;

    const float* xr = x + (size_t)t * DMODEL;
    uint16_t* xbr = xb + (size_t)t * DMODEL;
    float ag[8] = {0,0,0,0,0,0,0,0};
    float an[8] = {0,0,0,0,0,0,0,0};
    for (int j = 0; j < 16; ++j) {
        int idx = j * 64 + lane;
        float xv = xr[idx];
        xbr[idx] = f2bf(xv);
        const float4* gp  = (const float4*)(gate_w  + idx * 8);
        const float4* np_ = (const float4*)(noise_w + idx * 8);
        float4 g0 = gp[0], g1 = gp[1];
        float4 n0 = np_[0], n1 = np_[1];
        ag[0] += xv * g0.x; ag[1] += xv * g0.y; ag[2] += xv * g0.z; ag[3] += xv * g0.w;
        ag[4] += xv * g1.x; ag[5] += xv * g1.y; ag[6] += xv * g1.z; ag[7] += xv * g1.w;
        an[0] += xv * n0.x; an[1] += xv * n0.y; an[2] += xv * n0.z; an[3] += xv * n0.w;
        an[4] += xv * n1.x; an[5] += xv * n1.y; an[6] += xv * n1.z; an[7] += xv * n1.w;
    }
    #pragma unroll
    for (int m = 32; m >= 1; m >>= 1) {
        #pragma unroll
        for (int e = 0; e < 8; ++e) {
            ag[e] += __shfl_xor(ag[e], m, 64);
            an[e] += __shfl_xor(an[e], m, 64);
        }
    }
    float logit[8], sdv[8];
    #pragma unroll
    for (int e = 0; e < 8; ++e) {
        float a = an[e];
        float sp = (a > 20.0f) ? a : log1pf(expf(a));
        sdv[e] = sp;
        logit[e] = ag[e] + noise[(size_t)t * 8 + e] * sp;
    }
    // top-3 values, top-2 indices (strict > keeps earliest index, as lax.top_k)
    float v1 = -1e30f, v2 = -1e30f, v3 = -1e30f; int i1 = 0, i2 = 0;
    #pragma unroll
    for (int e = 0; e < 8; ++e) {
        float v = logit[e];
        if (v > v1)      { v3 = v2; v2 = v1; i2 = i1; v1 = v; i1 = e; }
        else if (v > v2) { v3 = v2; v2 = v; i2 = e; }
        else if (v > v3) { v3 = v; }
    }
    if (lane < 8) {
        float kth = (lane == i1 || lane == i2) ? v3 : v2;
        float z = (logit[lane] - kth) / sdv[lane];
        lp[wid][lane] = 0.5f * erfcf(-z * 0.70710678118654752440f);
    }
    if (lane == 0) {
        float e2 = expf(v2 - v1);
        float inv = 1.0f / (1.0f + e2);
        se1[wid] = i1; se2[wid] = i2;
        sw1[wid] = inv; sw2[wid] = e2 * inv;
    }
    __syncthreads();
    if (threadIdx.x < 8) {
        int e = threadIdx.x;
        // load-loss partial
        float s = 0.f;
        #pragma unroll
        for (int w = 0; w < 8; ++w) s += lp[w][e];
        atomicAdd(&loadAcc[e], s);
        // block-aggregated routing
        int m = 0;
        #pragma unroll
        for (int w = 0; w < 8; ++w) m += (se1[w] == e) + (se2[w] == e);
        if (m > 0) {
            int b = atomicAdd(&cnt[e], m);
            #pragma unroll
            for (int w = 0; w < 8; ++w) {
                int tok = blockIdx.x * 8 + w;
                if (se1[w] == e) {
                    if (b < CAP) { rowlist[e * CAP + b] = tok; slotw[e * CAP + b] = sw1[w]; }
                    b++;
                }
                if (se2[w] == e) {
                    if (b < CAP) { rowlist[e * CAP + b] = tok; slotw[e * CAP + b] = sw2[w]; }
                    b++;
                }
            }
        }
    }
}

// ---------------- block map scan: expert/row per 128-row packed block ----------------
__global__ void scan_kernel(const int* __restrict__ cnt,
                            int* __restrict__ be, int* __restrict__ brow)
{
    if (threadIdx.x == 0 && blockIdx.x == 0) {
        int idx = 0;
        for (int e = 0; e < NEXP; ++e) {
            int ce = cnt[e]; if (ce > CAP) ce = CAP;
            int nb = (ce + 127) >> 7;
            for (int k = 0; k < nb; ++k) { be[idx] = e; brow[idx] = k * 128; idx++; }
        }
        for (; idx < MAXBLK; ++idx) { be[idx] = -1; brow[idx] = 0; }
    }
}

// ---------------- per-expert transpose f32 [R][C] -> bf16 [C][R] ----------------
__global__ __launch_bounds__(256) void transpose_w_kernel(
    const float* __restrict__ src, uint16_t* __restrict__ dst, int R, int Cc)
{
    __shared__ float tile[32][33];
    const float* s = src + (size_t)blockIdx.z * R * Cc;
    uint16_t*    d = dst + (size_t)blockIdx.z * R * Cc;
    int c0 = blockIdx.x * 32, r0 = blockIdx.y * 32;
    int tx = threadIdx.x & 31, ty = threadIdx.x >> 5;
    #pragma unroll
    for (int rr = ty; rr < 32; rr += 8)
        tile[rr][tx] = s[(size_t)(r0 + rr) * Cc + c0 + tx];
    __syncthreads();
    #pragma unroll
    for (int rr = ty; rr < 32; rr += 8)
        d[(size_t)(c0 + rr) * R + r0 + tx] = f2bf(tile[tx][rr]);
}

// ---------------- GEMM: 128x128 tile, BK=32, 4 waves, m97 structure ----------------
// Packed-row grid: block rb covers packed rows [rb*128,(rb+1)*128) of one expert.
template<int KTOT, int GATHER, int GELU, int ATOMIC>
__global__ __launch_bounds__(256) void gemm_kernel(
    const uint16_t* __restrict__ Abase,
    const uint16_t* __restrict__ Bfull,
    const int*      __restrict__ rowlist,
    const float*    __restrict__ slotw,
    const int*      __restrict__ cnt,
    const int*      __restrict__ be,
    const int*      __restrict__ brow,
    const float*    __restrict__ biasFull,
    uint16_t*       __restrict__ OutBf,
    float*          __restrict__ OutF,
    int ncols, int bo)
{
    __shared__ uint16_t lA[4096];   // 128x32 bf16, fragment-contiguous
    __shared__ uint16_t lB[4096];
    __shared__ int   lT[128];
    __shared__ float lW[128];

    const int rb = blockIdx.x + bo;
    if (rb >= MAXBLK) return;
    const int e = be[rb];
    if (e < 0) return;
    const int row0 = brow[rb];
    int ce = cnt[e]; if (ce > CAP) ce = CAP;
    const int n0 = blockIdx.y * 128;

    const int t = threadIdx.x;
    const int lane = t & 63;
    const int wid = t >> 6;
    const int fr = lane & 15;
    const int ks = lane >> 4;

    if (GATHER || ATOMIC) {
        if (t < 128) {
            int r = row0 + t;
            int rc = (r < ce) ? r : (ce - 1);
            lT[t] = rowlist[e * CAP + rc];
            if (ATOMIC) lW[t] = (r < ce) ? slotw[e * CAP + r] : 0.0f;
        }
        __syncthreads();
    }

    const int ra0 = wid * 16 + fr;
    const int ra1 = 64 + wid * 16 + fr;
    size_t arow0, arow1;
    if (GATHER) { arow0 = (size_t)lT[ra0]; arow1 = (size_t)lT[ra1]; }
    else        { arow0 = (size_t)blockIdx.x * 128 + ra0;
                  arow1 = (size_t)blockIdx.x * 128 + ra1; }
    const uint16_t* pA0 = Abase + arow0 * KTOT + ks * 8;
    const uint16_t* pA1 = Abase + arow1 * KTOT + ks * 8;
    const uint16_t* Bp  = Bfull + (size_t)e * ncols * KTOT;
    const uint16_t* pB0 = Bp + (size_t)(n0 + ra0) * KTOT + ks * 8;
    const uint16_t* pB1 = Bp + (size_t)(n0 + ra1) * KTOT + ks * 8;
    uint16_t* dA0 = &lA[t * 8];
    uint16_t* dA1 = &lA[2048 + t * 8];
    uint16_t* dB0 = &lB[t * 8];
    uint16_t* dB1 = &lB[2048 + t * 8];

    f32x4 acc[4][4];
    #pragma unroll
    for (int a = 0; a < 4; ++a)
        #pragma unroll
        for (int b = 0; b < 4; ++b) acc[a][b] = (f32x4){0.f, 0.f, 0.f, 0.f};

    const int wr = wid >> 1, wc = wid & 1;

    for (int k0 = 0; k0 < KTOT; k0 += 32) {
        glds16(pA0 + k0, dA0);
        glds16(pA1 + k0, dA1);
        glds16(pB0 + k0, dB0);
        glds16(pB1 + k0, dB1);
        __syncthreads();
        short8 af[4], bfr[4];
        #pragma unroll
        for (int mi = 0; mi < 4; ++mi)
            af[mi] = *(const short8*)&lA[(wr * 4 + mi) * 512 + lane * 8];
        #pragma unroll
        for (int ni = 0; ni < 4; ++ni)
            bfr[ni] = *(const short8*)&lB[(wc * 4 + ni) * 512 + lane * 8];
        #pragma unroll
        for (int mi = 0; mi < 4; ++mi)
            #pragma unroll
            for (int ni = 0; ni < 4; ++ni)
                acc[mi][ni] = __builtin_amdgcn_mfma_f32_16x16x32_bf16(
                    af[mi], bfr[ni], acc[mi][ni], 0, 0, 0);
        __syncthreads();
    }

    // epilogue: D mapping col = lane&15, row = (lane>>4)*4 + j  [m89/m91]
    const int colBase = n0 + wc * 64;
    const float* bias = biasFull + (size_t)e * ncols;
    #pragma unroll
    for (int mi = 0; mi < 4; ++mi) {
        int rloc = wr * 64 + mi * 16 + ks * 4;
        #pragma unroll
        for (int ni = 0; ni < 4; ++ni) {
            int c = colBase + ni * 16 + fr;
            float bv = bias[c];
            #pragma unroll
            for (int j = 0; j < 4; ++j) {
                float v = acc[mi][ni][j] + bv;
                if (GELU) v = gelu_tanh(v);
                int rl = rloc + j;
                if (ATOMIC) {
                    if (row0 + rl < ce)
                        atomicAdd(&OutF[(size_t)lT[rl] * DMODEL + c], lW[rl] * v);
                } else {
                    OutBf[((size_t)blockIdx.x * 128 + rl) * ncols + c] = f2bf(v);
                }
            }
        }
    }
}

// ---------------- load-loss finalize ----------------
__global__ void finalize_kernel(const float* __restrict__ loadAcc, float* __restrict__ out) {
    if (threadIdx.x == 0) {
        float m = 0.f;
        #pragma unroll
        for (int e = 0; e < 8; ++e) m += loadAcc[e];
        m *= 0.125f;
        float v = 0.f;
        #pragma unroll
        for (int e = 0; e < 8; ++e) { float d0 = loadAcc[e] - m; v += d0 * d0; }
        v *= (1.0f / 7.0f);   // ddof=1
        out[(size_t)N_TOK * DMODEL] = W_LOAD_C * v / (m * m);
    }
}

extern "C" void kernel_launch(void* const* d_in, const int* in_sizes, int n_in,
                              void* d_out, int out_size, void* d_ws, size_t ws_size,
                              hipStream_t stream) {
    const float* x       = (const float*)d_in[0];
    const float* noise   = (const float*)d_in[1];
    const float* gate_w  = (const float*)d_in[2];
    const float* noise_w = (const float*)d_in[3];
    const float* w1      = (const float*)d_in[4];
    const float* b1      = (const float*)d_in[5];
    const float* w2      = (const float*)d_in[6];
    const float* b2      = (const float*)d_in[7];
    float* out = (float*)d_out;
    char* ws = (char*)d_ws;

    int*      cnt     = (int*)(ws + 0);
    float*    loadAcc = (float*)(ws + 256);
    int*      be      = (int*)(ws + 1024);
    int*      brow    = (int*)(ws + 3072);
    int*      rowlist = (int*)(ws + 8192);
    float*    slotw   = (float*)(ws + 270336);
    uint16_t* xb      = (uint16_t*)(ws + 532480);
    uint16_t* w1t     = (uint16_t*)(ws + 34086912);
    uint16_t* w2t     = (uint16_t*)(ws + 101195776);
    uint16_t* h       = (uint16_t*)(ws + 168304640);
    const size_t HOFF = 168304640ull;

    // pick chunk count so packed-h fits the workspace
    size_t avail = (ws_size > HOFF) ? ws_size - HOFF : 0;
    int nch = 8, bpc = (MAXBLK + 7) / 8;
    for (int c = 1; c <= 8; c <<= 1) {
        int b = (MAXBLK + c - 1) / c;
        if ((size_t)b * 128 * DFF * 2 <= avail) { nch = c; bpc = b; break; }
    }

    hipMemsetAsync(ws, 0, 8192, stream);
    hipMemsetAsync(d_out, 0, (size_t)out_size * sizeof(float), stream);

    gating_kernel<<<2048, 512, 0, stream>>>(x, noise, gate_w, noise_w,
                                            cnt, loadAcc, rowlist, slotw, xb);
    scan_kernel<<<1, 64, 0, stream>>>(cnt, be, brow);
    transpose_w_kernel<<<dim3(128, 32, 8), 256, 0, stream>>>(w1, w1t, 1024, 4096);
    transpose_w_kernel<<<dim3(32, 128, 8), 256, 0, stream>>>(w2, w2t, 4096, 1024);
    finalize_kernel<<<1, 64, 0, stream>>>(loadAcc, out);

    for (int c = 0; c < nch; ++c) {
        int bo = c * bpc;
        if (bo >= MAXBLK) break;
        gemm_kernel<1024, 1, 1, 0><<<dim3(bpc, 32), 256, 0, stream>>>(
            xb, w1t, rowlist, slotw, cnt, be, brow, b1, h, nullptr, DFF, bo);
        gemm_kernel<4096, 0, 0, 1><<<dim3(bpc, 8), 256, 0, stream>>>(
            h, w2t, rowlist, slotw, cnt, be, brow, b2, nullptr, out, DMODEL, bo);
    }
}

// Round 3
// 1437.711 us; speedup vs baseline: 1.8517x; 1.0203x over previous
//
#include <hip/hip_runtime.h>
#include <stdint.h>

#define N_TOK   16384
#define DMODEL  1024
#define NEXP    8
#define DFF     4096
#define CAP     8192
#define MAXBLK  264          // 32768/128 + 8 (per-expert 128-row padding)
#define W_LOAD_C 0.01f

typedef __attribute__((ext_vector_type(8))) short short8;
typedef __attribute__((ext_vector_type(4))) float f32x4;

__device__ __forceinline__ uint16_t f2bf(float f) {
    uint32_t u = __float_as_uint(f);
    uint32_t r = u + 0x7fffu + ((u >> 16) & 1u);
    return (uint16_t)(r >> 16);
}

__device__ __forceinline__ float gelu_tanh(float v) {
    float u = 0.7978845608028654f * (v + 0.044715f * v * v * v);
    float ex = __expf(2.0f * u);
    float th = 1.0f - 2.0f / (ex + 1.0f);
    return 0.5f * v * (1.0f + th);
}

__device__ __forceinline__ void glds16(const uint16_t* g, uint16_t* l) {
    __builtin_amdgcn_global_load_lds(
        (const __attribute__((address_space(1))) void*)g,
        (__attribute__((address_space(3))) void*)l, 16, 0, 0);
}

// ---------------- gating + routing + load-loss + fused x->bf16 ----------------
// 2048 blocks x 512 threads; one token per wave. Dot-product code kept
// bitwise-identical to the round-1/2 passing version (same FMA/shuffle order).
__global__ __launch_bounds__(512) void gating_kernel(
    const float* __restrict__ x, const float* __restrict__ noise,
    const float* __restrict__ gate_w, const float* __restrict__ noise_w,
    int* __restrict__ cnt, float* __restrict__ loadAcc,
    int* __restrict__ rowlist, float* __restrict__ slotw,
    uint16_t* __restrict__ xb)
{
    __shared__ float lp[8][8];
    __shared__ int   se1[8], se2[8];
    __shared__ float sw1[8], sw2[8];

    const int lane = threadIdx.x & 63;
    const int wid  = threadIdx.x >> 6;
    const int t = blockIdx.x * 8 + wid;

    const float* xr = x + (size_t)t * DMODEL;
    uint16_t* xbr = xb + (size_t)t * DMODEL;
    float ag[8] = {0,0,0,0,0,0,0,0};
    float an[8] = {0,0,0,0,0,0,0,0};
    for (int j = 0; j < 16; ++j) {
        int idx = j * 64 + lane;
        float xv = xr[idx];
        xbr[idx] = f2bf(xv);
        const float4* gp  = (const float4*)(gate_w  + idx * 8);
        const float4* np_ = (const float4*)(noise_w + idx * 8);
        float4 g0 = gp[0], g1 = gp[1];
        float4 n0 = np_[0], n1 = np_[1];
        ag[0] += xv * g0.x; ag[1] += xv * g0.y; ag[2] += xv * g0.z; ag[3] += xv * g0.w;
        ag[4] += xv * g1.x; ag[5] += xv * g1.y; ag[6] += xv * g1.z; ag[7] += xv * g1.w;
        an[0] += xv * n0.x; an[1] += xv * n0.y; an[2] += xv * n0.z; an[3] += xv * n0.w;
        an[4] += xv * n1.x; an[5] += xv * n1.y; an[6] += xv * n1.z; an[7] += xv * n1.w;
    }
    #pragma unroll
    for (int m = 32; m >= 1; m >>= 1) {
        #pragma unroll
        for (int e = 0; e < 8; ++e) {
            ag[e] += __shfl_xor(ag[e], m, 64);
            an[e] += __shfl_xor(an[e], m, 64);
        }
    }
    float logit[8], sdv[8];
    #pragma unroll
    for (int e = 0; e < 8; ++e) {
        float a = an[e];
        float sp = (a > 20.0f) ? a : log1pf(expf(a));
        sdv[e] = sp;
        logit[e] = ag[e] + noise[(size_t)t * 8 + e] * sp;
    }
    // top-3 values, top-2 indices (strict > keeps earliest index, as lax.top_k)
    float v1 = -1e30f, v2 = -1e30f, v3 = -1e30f; int i1 = 0, i2 = 0;
    #pragma unroll
    for (int e = 0; e < 8; ++e) {
        float v = logit[e];
        if (v > v1)      { v3 = v2; v2 = v1; i2 = i1; v1 = v; i1 = e; }
        else if (v > v2) { v3 = v2; v2 = v; i2 = e; }
        else if (v > v3) { v3 = v; }
    }
    if (lane < 8) {
        float kth = (lane == i1 || lane == i2) ? v3 : v2;
        float z = (logit[lane] - kth) / sdv[lane];
        lp[wid][lane] = 0.5f * erfcf(-z * 0.70710678118654752440f);
    }
    if (lane == 0) {
        float e2 = expf(v2 - v1);
        float inv = 1.0f / (1.0f + e2);
        se1[wid] = i1; se2[wid] = i2;
        sw1[wid] = inv; sw2[wid] = e2 * inv;
    }
    __syncthreads();
    if (threadIdx.x < 8) {
        int e = threadIdx.x;
        // load-loss partial
        float s = 0.f;
        #pragma unroll
        for (int w = 0; w < 8; ++w) s += lp[w][e];
        atomicAdd(&loadAcc[e], s);
        // block-aggregated routing
        int m = 0;
        #pragma unroll
        for (int w = 0; w < 8; ++w) m += (se1[w] == e) + (se2[w] == e);
        if (m > 0) {
            int b = atomicAdd(&cnt[e], m);
            #pragma unroll
            for (int w = 0; w < 8; ++w) {
                int tok = blockIdx.x * 8 + w;
                if (se1[w] == e) {
                    if (b < CAP) { rowlist[e * CAP + b] = tok; slotw[e * CAP + b] = sw1[w]; }
                    b++;
                }
                if (se2[w] == e) {
                    if (b < CAP) { rowlist[e * CAP + b] = tok; slotw[e * CAP + b] = sw2[w]; }
                    b++;
                }
            }
        }
    }
}

// ---------------- block map scan: expert/row per 128-row packed block ----------------
__global__ void scan_kernel(const int* __restrict__ cnt,
                            int* __restrict__ be, int* __restrict__ brow)
{
    if (threadIdx.x == 0 && blockIdx.x == 0) {
        int idx = 0;
        for (int e = 0; e < NEXP; ++e) {
            int ce = cnt[e]; if (ce > CAP) ce = CAP;
            int nb = (ce + 127) >> 7;
            for (int k = 0; k < nb; ++k) { be[idx] = e; brow[idx] = k * 128; idx++; }
        }
        for (; idx < MAXBLK; ++idx) { be[idx] = -1; brow[idx] = 0; }
    }
}

// ---------------- per-expert transpose f32 [R][C] -> bf16 [C][R] ----------------
__global__ __launch_bounds__(256) void transpose_w_kernel(
    const float* __restrict__ src, uint16_t* __restrict__ dst, int R, int Cc)
{
    __shared__ float tile[32][33];
    const float* s = src + (size_t)blockIdx.z * R * Cc;
    uint16_t*    d = dst + (size_t)blockIdx.z * R * Cc;
    int c0 = blockIdx.x * 32, r0 = blockIdx.y * 32;
    int tx = threadIdx.x & 31, ty = threadIdx.x >> 5;
    #pragma unroll
    for (int rr = ty; rr < 32; rr += 8)
        tile[rr][tx] = s[(size_t)(r0 + rr) * Cc + c0 + tx];
    __syncthreads();
    #pragma unroll
    for (int rr = ty; rr < 32; rr += 8)
        d[(size_t)(c0 + rr) * R + r0 + tx] = f2bf(tile[tx][rr]);
}

// ---------------- GEMM: 128x128 tile, BK=32, 4 waves, 2-phase LDS dbuf ----------------
// Grid: blockIdx.x = column panel (fast, for A-panel L2 reuse), blockIdx.y = row block.
// 2-phase recipe (T3-minimum): STAGE(next) issued BEFORE compute(cur); single
// __syncthreads per K-step (compiler emits the vmcnt(0)+lgkmcnt(0) drain there).
template<int KTOT, int GATHER, int GELU, int ATOMIC>
__global__ __launch_bounds__(256) void gemm_kernel(
    const uint16_t* __restrict__ Abase,
    const uint16_t* __restrict__ Bfull,
    const int*      __restrict__ rowlist,
    const float*    __restrict__ slotw,
    const int*      __restrict__ cnt,
    const int*      __restrict__ be,
    const int*      __restrict__ brow,
    const float*    __restrict__ biasFull,
    uint16_t*       __restrict__ OutBf,
    float*          __restrict__ OutF,
    int ncols, int bo)
{
    __shared__ uint16_t lA[2][4096];   // 2 x (128x32) bf16, fragment-contiguous
    __shared__ uint16_t lB[2][4096];
    __shared__ int   lT[128];
    __shared__ float lW[128];

    const int rb = blockIdx.y + bo;
    if (rb >= MAXBLK) return;
    const int e = be[rb];
    if (e < 0) return;
    const int row0 = brow[rb];
    int ce = cnt[e]; if (ce > CAP) ce = CAP;
    const int n0 = blockIdx.x * 128;

    const int t = threadIdx.x;
    const int lane = t & 63;
    const int wid = t >> 6;
    const int fr = lane & 15;
    const int ks = lane >> 4;

    if (GATHER || ATOMIC) {
        if (t < 128) {
            int r = row0 + t;
            int rc = (r < ce) ? r : (ce - 1);
            lT[t] = rowlist[e * CAP + rc];
            if (ATOMIC) lW[t] = (r < ce) ? slotw[e * CAP + r] : 0.0f;
        }
        __syncthreads();
    }

    const int ra0 = wid * 16 + fr;
    const int ra1 = 64 + wid * 16 + fr;
    size_t arow0, arow1;
    if (GATHER) { arow0 = (size_t)lT[ra0]; arow1 = (size_t)lT[ra1]; }
    else        { arow0 = (size_t)blockIdx.y * 128 + ra0;
                  arow1 = (size_t)blockIdx.y * 128 + ra1; }
    const uint16_t* pA0 = Abase + arow0 * KTOT + ks * 8;
    const uint16_t* pA1 = Abase + arow1 * KTOT + ks * 8;
    const uint16_t* Bp  = Bfull + (size_t)e * ncols * KTOT;
    const uint16_t* pB0 = Bp + (size_t)(n0 + ra0) * KTOT + ks * 8;
    const uint16_t* pB1 = Bp + (size_t)(n0 + ra1) * KTOT + ks * 8;

    f32x4 acc[4][4];
    #pragma unroll
    for (int a = 0; a < 4; ++a)
        #pragma unroll
        for (int b = 0; b < 4; ++b) acc[a][b] = (f32x4){0.f, 0.f, 0.f, 0.f};

    const int wr = wid >> 1, wc = wid & 1;
    constexpr int NT = KTOT / 32;

    // prologue: stage tile 0 into buffer 0
    glds16(pA0, &lA[0][t * 8]);
    glds16(pA1, &lA[0][2048 + t * 8]);
    glds16(pB0, &lB[0][t * 8]);
    glds16(pB1, &lB[0][2048 + t * 8]);
    __syncthreads();   // drains vmcnt -> buf0 ready

    for (int tk = 0; tk < NT; ++tk) {
        const int cur = tk & 1;
        // issue next tile's loads into the other buffer (overlaps with compute)
        if (tk + 1 < NT) {
            const int k1 = (tk + 1) * 32;
            glds16(pA0 + k1, &lA[cur ^ 1][t * 8]);
            glds16(pA1 + k1, &lA[cur ^ 1][2048 + t * 8]);
            glds16(pB0 + k1, &lB[cur ^ 1][t * 8]);
            glds16(pB1 + k1, &lB[cur ^ 1][2048 + t * 8]);
        }
        short8 af[4], bfr[4];
        #pragma unroll
        for (int mi = 0; mi < 4; ++mi)
            af[mi] = *(const short8*)&lA[cur][(wr * 4 + mi) * 512 + lane * 8];
        #pragma unroll
        for (int ni = 0; ni < 4; ++ni)
            bfr[ni] = *(const short8*)&lB[cur][(wc * 4 + ni) * 512 + lane * 8];
        #pragma unroll
        for (int mi = 0; mi < 4; ++mi)
            #pragma unroll
            for (int ni = 0; ni < 4; ++ni)
                acc[mi][ni] = __builtin_amdgcn_mfma_f32_16x16x32_bf16(
                    af[mi], bfr[ni], acc[mi][ni], 0, 0, 0);
        __syncthreads();   // one barrier per K-step: drains stage writes,
                           // and frees buf[cur] for the next iteration's stage
    }

    // epilogue: D mapping col = lane&15, row = (lane>>4)*4 + j  [m89/m91]
    const int colBase = n0 + wc * 64;
    const float* bias = biasFull + (size_t)e * ncols;
    #pragma unroll
    for (int mi = 0; mi < 4; ++mi) {
        int rloc = wr * 64 + mi * 16 + ks * 4;
        #pragma unroll
        for (int ni = 0; ni < 4; ++ni) {
            int c = colBase + ni * 16 + fr;
            float bv = bias[c];
            #pragma unroll
            for (int j = 0; j < 4; ++j) {
                float v = acc[mi][ni][j] + bv;
                if (GELU) v = gelu_tanh(v);
                int rl = rloc + j;
                if (ATOMIC) {
                    if (row0 + rl < ce)
                        atomicAdd(&OutF[(size_t)lT[rl] * DMODEL + c], lW[rl] * v);
                } else {
                    OutBf[((size_t)blockIdx.y * 128 + rl) * ncols + c] = f2bf(v);
                }
            }
        }
    }
}

// ---------------- load-loss finalize ----------------
__global__ void finalize_kernel(const float* __restrict__ loadAcc, float* __restrict__ out) {
    if (threadIdx.x == 0) {
        float m = 0.f;
        #pragma unroll
        for (int e = 0; e < 8; ++e) m += loadAcc[e];
        m *= 0.125f;
        float v = 0.f;
        #pragma unroll
        for (int e = 0; e < 8; ++e) { float d0 = loadAcc[e] - m; v += d0 * d0; }
        v *= (1.0f / 7.0f);   // ddof=1
        out[(size_t)N_TOK * DMODEL] = W_LOAD_C * v / (m * m);
    }
}

extern "C" void kernel_launch(void* const* d_in, const int* in_sizes, int n_in,
                              void* d_out, int out_size, void* d_ws, size_t ws_size,
                              hipStream_t stream) {
    const float* x       = (const float*)d_in[0];
    const float* noise   = (const float*)d_in[1];
    const float* gate_w  = (const float*)d_in[2];
    const float* noise_w = (const float*)d_in[3];
    const float* w1      = (const float*)d_in[4];
    const float* b1      = (const float*)d_in[5];
    const float* w2      = (const float*)d_in[6];
    const float* b2      = (const float*)d_in[7];
    float* out = (float*)d_out;
    char* ws = (char*)d_ws;

    int*      cnt     = (int*)(ws + 0);
    float*    loadAcc = (float*)(ws + 256);
    int*      be      = (int*)(ws + 1024);
    int*      brow    = (int*)(ws + 3072);
    int*      rowlist = (int*)(ws + 8192);
    float*    slotw   = (float*)(ws + 270336);
    uint16_t* xb      = (uint16_t*)(ws + 532480);
    uint16_t* w1t     = (uint16_t*)(ws + 34086912);
    uint16_t* w2t     = (uint16_t*)(ws + 101195776);
    uint16_t* h       = (uint16_t*)(ws + 168304640);
    const size_t HOFF = 168304640ull;

    // pick chunk count so packed-h fits the workspace
    size_t avail = (ws_size > HOFF) ? ws_size - HOFF : 0;
    int nch = 8, bpc = (MAXBLK + 7) / 8;
    for (int c = 1; c <= 8; c <<= 1) {
        int b = (MAXBLK + c - 1) / c;
        if ((size_t)b * 128 * DFF * 2 <= avail) { nch = c; bpc = b; break; }
    }

    hipMemsetAsync(ws, 0, 8192, stream);
    hipMemsetAsync(d_out, 0, (size_t)out_size * sizeof(float), stream);

    gating_kernel<<<2048, 512, 0, stream>>>(x, noise, gate_w, noise_w,
                                            cnt, loadAcc, rowlist, slotw, xb);
    scan_kernel<<<1, 64, 0, stream>>>(cnt, be, brow);
    transpose_w_kernel<<<dim3(128, 32, 8), 256, 0, stream>>>(w1, w1t, 1024, 4096);
    transpose_w_kernel<<<dim3(32, 128, 8), 256, 0, stream>>>(w2, w2t, 4096, 1024);
    finalize_kernel<<<1, 64, 0, stream>>>(loadAcc, out);

    for (int c = 0; c < nch; ++c) {
        int bo = c * bpc;
        if (bo >= MAXBLK) break;
        gemm_kernel<1024, 1, 1, 0><<<dim3(32, bpc), 256, 0, stream>>>(
            xb, w1t, rowlist, slotw, cnt, be, brow, b1, h, nullptr, DFF, bo);
        gemm_kernel<4096, 0, 0, 1><<<dim3(8, bpc), 256, 0, stream>>>(
            h, w2t, rowlist, slotw, cnt, be, brow, b2, nullptr, out, DMODEL, bo);
    }
}